// Round 1
// baseline (472.125 us; speedup 1.0000x reference)
//
#include <hip/hip_runtime.h>
#include <hip/hip_bf16.h>

typedef short short8 __attribute__((ext_vector_type(8)));
typedef float f32x4 __attribute__((ext_vector_type(4)));

#define BM 128
#define BN 128
#define BK_ 32
#define LDT 40  // BK_ + 8 pad; row pitch 80B stays 16B-aligned for ds_read_b128

__device__ __forceinline__ unsigned short f2bf(float f) {
  unsigned int u = __float_as_uint(f);
  u += 0x7FFFu + ((u >> 16) & 1u);   // round-to-nearest-even
  return (unsigned short)(u >> 16);
}

struct GemmP {
  const unsigned short* A;
  const unsigned short* Bm;
  void* C;
  const float* mask_p;
  const float* mask_s;
  const float* bias;
  long long sAb, sAh, sBb, sBh, sCb, sCh;  // batch strides in elements; z -> (zb=z/Hh, zh=z%Hh)
  int lda, ldb, ldc, M, N, K, Hh;
};

// TA: 0 = A is M x K row-major; 1 = A stored K x M row-major (logical A = stored^T)
// TB: 0 = B is K x N row-major; 1 = B stored N x K row-major
// EPI: 0 = store bf16; 1 = tanh*mask store bf16; 2 = relu + atomic max into f32 pool; 3 = +bias, relu, store f32
template <int TA, int TB, int EPI>
__global__ __launch_bounds__(256) void gemm_k(GemmP p) {
  __shared__ __align__(16) unsigned short As[BM * LDT];
  __shared__ __align__(16) unsigned short Bs[BN * LDT];

  const int z = blockIdx.z;
  const int zb = z / p.Hh, zh = z % p.Hh;
  const unsigned short* A = p.A + (size_t)zb * p.sAb + (size_t)zh * p.sAh;
  const unsigned short* B = p.Bm + (size_t)zb * p.sBb + (size_t)zh * p.sBh;
  const int m0 = blockIdx.x * BM, n0 = blockIdx.y * BN;
  const int tid = threadIdx.x;
  const int wid = tid >> 6, lane = tid & 63;
  const int wm = (wid >> 1) * 64, wn = (wid & 1) * 64;
  const int lrow = lane & 15, lkg = lane >> 4;

  f32x4 acc[4][4] = {};

  for (int k0 = 0; k0 < p.K; k0 += BK_) {
    if (TA == 0) {
      const int m = tid >> 2, kg = tid & 3;
#pragma unroll
      for (int q = 0; q < 2; ++q) {
        const unsigned short* src = A + (size_t)(m0 + m + q * 64) * p.lda + (k0 + kg * 8);
        *(uint4*)&As[(m + q * 64) * LDT + kg * 8] = *(const uint4*)src;
      }
    } else {
      const int kk = tid & 31, mg = (tid >> 5) << 4;
      const unsigned short* src = A + (size_t)(k0 + kk) * p.lda + (m0 + mg);
      uint4 v0 = *(const uint4*)src;
      uint4 v1 = *(const uint4*)(src + 8);
      unsigned short tmp[16];
      *(uint4*)&tmp[0] = v0;
      *(uint4*)&tmp[8] = v1;
#pragma unroll
      for (int j = 0; j < 16; ++j) As[(mg + j) * LDT + kk] = tmp[j];
    }
    if (TB == 1) {
      const int n = tid >> 2, kg = tid & 3;
#pragma unroll
      for (int q = 0; q < 2; ++q) {
        const unsigned short* src = B + (size_t)(n0 + n + q * 64) * p.ldb + (k0 + kg * 8);
        *(uint4*)&Bs[(n + q * 64) * LDT + kg * 8] = *(const uint4*)src;
      }
    } else {
      const int kk = tid & 31, ng = (tid >> 5) << 4;
      const unsigned short* src = B + (size_t)(k0 + kk) * p.ldb + (n0 + ng);
      uint4 v0 = *(const uint4*)src;
      uint4 v1 = *(const uint4*)(src + 8);
      unsigned short tmp[16];
      *(uint4*)&tmp[0] = v0;
      *(uint4*)&tmp[8] = v1;
#pragma unroll
      for (int j = 0; j < 16; ++j) Bs[(ng + j) * LDT + kk] = tmp[j];
    }
    __syncthreads();

    short8 af[4], bfv[4];
#pragma unroll
    for (int mt = 0; mt < 4; ++mt)
      af[mt] = *(const short8*)&As[(wm + mt * 16 + lrow) * LDT + lkg * 8];
#pragma unroll
    for (int nt = 0; nt < 4; ++nt)
      bfv[nt] = *(const short8*)&Bs[(wn + nt * 16 + lrow) * LDT + lkg * 8];
#pragma unroll
    for (int mt = 0; mt < 4; ++mt)
#pragma unroll
      for (int nt = 0; nt < 4; ++nt)
        acc[mt][nt] = __builtin_amdgcn_mfma_f32_16x16x32_bf16(af[mt], bfv[nt], acc[mt][nt], 0, 0, 0);
    __syncthreads();
  }

  unsigned short* Cu = (unsigned short*)p.C + (size_t)zb * p.sCb + (size_t)zh * p.sCh;
  float* Cf = (float*)p.C + (size_t)zb * p.sCb + (size_t)zh * p.sCh;

#pragma unroll
  for (int mt = 0; mt < 4; ++mt) {
#pragma unroll
    for (int nt = 0; nt < 4; ++nt) {
      f32x4 a = acc[mt][nt];
#pragma unroll
      for (int r = 0; r < 4; ++r) {
        const int grow = m0 + wm + mt * 16 + lkg * 4 + r;  // C/D: row=(lane>>4)*4+reg
        const int gcol = n0 + wn + nt * 16 + lrow;         //      col=lane&15
        const float v = a[r];
        if constexpr (EPI == 0) {
          Cu[(size_t)grow * p.ldc + gcol] = f2bf(v);
        } else if constexpr (EPI == 1) {
          const float mm = p.mask_p[(size_t)zb * p.M + grow] * p.mask_s[(size_t)zb * p.N + gcol];
          Cu[(size_t)grow * p.ldc + gcol] = f2bf(tanhf(v) * mm);
        } else if constexpr (EPI == 2) {
          // relu output >= 0, pool initialized to 0 -> int compare == float compare
          atomicMax((int*)Cf + (size_t)grow * p.ldc + gcol, __float_as_int(fmaxf(v, 0.f)));
        } else {
          Cf[(size_t)grow * p.ldc + gcol] = fmaxf(v + p.bias[gcol], 0.f);
        }
      }
    }
  }
}

__global__ void cvt_bf16(const float* in, unsigned short* out, int n) {
  int i = blockIdx.x * 256 + threadIdx.x;
  if (i < n) out[i] = f2bf(in[i]);
}

// out[z][c][r] = in[z][r][c]  (fp32 -> bf16, batched transpose)
__global__ void trans_bf16(const float* in, unsigned short* out, int Z, int R, int C) {
  int i = blockIdx.x * 256 + threadIdx.x;
  if (i >= Z * R * C) return;
  int z = i / (R * C), rem = i % (R * C);
  int c = rem / R, r = rem % R;
  out[i] = f2bf(in[(size_t)z * R * C + (size_t)r * C + c]);
}

// out[r][0..D) = X[r][*] (bf16 copy), out[r][D..D+HD) = bf16(pool[r][*])
__global__ void concat_k(const unsigned short* X, const float* pool, unsigned short* out,
                         int rows, int Dd, int HDd) {
  const int W = Dd + HDd;
  int i = blockIdx.x * 256 + threadIdx.x;
  if (i >= rows * W) return;
  int r = i / W, c = i % W;
  out[i] = (c < Dd) ? X[(size_t)r * Dd + c] : f2bf(pool[(size_t)r * HDd + (c - Dd)]);
}

template <int TA, int TB, int EPI>
static inline void run_gemm(const GemmP& q, int Z, hipStream_t stream) {
  dim3 grid(q.M / BM, q.N / BN, Z);
  gemm_k<TA, TB, EPI><<<grid, dim3(256), 0, stream>>>(q);
}

extern "C" void kernel_launch(void* const* d_in, const int* in_sizes, int n_in,
                              void* d_out, int out_size, void* d_ws, size_t ws_size,
                              hipStream_t stream) {
  (void)in_sizes; (void)n_in; (void)out_size;
  const float* primary   = (const float*)d_in[0];
  const float* secondary = (const float*)d_in[1];
  const float* pmask     = (const float*)d_in[2];
  const float* smask     = (const float*)d_in[3];
  const float* W_aff     = (const float*)d_in[4];
  const float* W_p       = (const float*)d_in[5];
  const float* W_s       = (const float*)d_in[6];
  const float* W_fp      = (const float*)d_in[7];
  const float* b_fp      = (const float*)d_in[8];
  const float* W_fs      = (const float*)d_in[9];
  const float* b_fs      = (const float*)d_in[10];

  constexpr int Bb = 16, L = 512, Dd = 512, Hh = 8, HDd = 128, INNER = 1024, CAT = 640;
  constexpr long long LD = (long long)L * Dd;  // 262144
  constexpr long long LL = (long long)L * L;   // 262144

  char* base = (char*)d_ws;
  size_t off = 0;
  auto alloc = [&](size_t bytes) -> void* {
    void* r = base + off;
    off += (bytes + 255) & ~(size_t)255;
    return r;
  };

  unsigned short* Pbf  = (unsigned short*)alloc((size_t)Bb * L * Dd * 2);
  unsigned short* Sbf  = (unsigned short*)alloc((size_t)Bb * L * Dd * 2);
  unsigned short* WaT  = (unsigned short*)alloc((size_t)Hh * Dd * Dd * 2);   // [h][f][e]
  unsigned short* WpT  = (unsigned short*)alloc((size_t)INNER * Dd * 2);     // [n][e]
  unsigned short* WsT  = (unsigned short*)alloc((size_t)INNER * Dd * 2);
  unsigned short* WfpT = (unsigned short*)alloc((size_t)Dd * CAT * 2);       // [n][k]
  unsigned short* WfsT = (unsigned short*)alloc((size_t)Dd * CAT * 2);
  unsigned short* pp   = (unsigned short*)alloc((size_t)Bb * L * INNER * 2); // (B*L1, H*HD)
  unsigned short* psb  = (unsigned short*)alloc((size_t)Bb * L * INNER * 2); // (B*L2, H*HD)
  unsigned short* catP = (unsigned short*)alloc((size_t)Bb * L * CAT * 2);
  unsigned short* catS = (unsigned short*)alloc((size_t)Bb * L * CAT * 2);
  float* pool_p = (float*)alloc((size_t)Bb * L * HDd * 4);
  float* pool_s = (float*)alloc((size_t)Bb * L * HDd * 4);

  const size_t fullT = (size_t)Bb * Hh * L * Dd * 2;  // 64 MiB each for T and aff
  const bool full = (off + 2 * (fullT + 256)) <= ws_size;
  unsigned short* Tb   = (unsigned short*)alloc(full ? fullT : (size_t)Bb * L * Dd * 2);
  unsigned short* affb = (unsigned short*)alloc(full ? fullT : (size_t)Bb * L * L * 2);

  // ---- convert inputs, transpose weights to N x K ----
  {
    const int n = Bb * L * Dd;
    cvt_bf16<<<dim3(n / 256), dim3(256), 0, stream>>>(primary, Pbf, n);
    cvt_bf16<<<dim3(n / 256), dim3(256), 0, stream>>>(secondary, Sbf, n);
  }
  trans_bf16<<<dim3((Hh * Dd * Dd) / 256), dim3(256), 0, stream>>>(W_aff, WaT, Hh, Dd, Dd);
  trans_bf16<<<dim3((Dd * INNER) / 256), dim3(256), 0, stream>>>(W_p, WpT, 1, Dd, INNER);
  trans_bf16<<<dim3((Dd * INNER) / 256), dim3(256), 0, stream>>>(W_s, WsT, 1, Dd, INNER);
  trans_bf16<<<dim3((CAT * Dd) / 256), dim3(256), 0, stream>>>(W_fp, WfpT, 1, CAT, Dd);
  trans_bf16<<<dim3((CAT * Dd) / 256), dim3(256), 0, stream>>>(W_fs, WfsT, 1, CAT, Dd);

  hipMemsetAsync(pool_p, 0, (size_t)Bb * L * HDd * 4, stream);
  hipMemsetAsync(pool_s, 0, (size_t)Bb * L * HDd * 4, stream);

  // ---- pp = P @ W_p ; ps = S @ W_s ----
  {
    GemmP g{};
    g.A = Pbf; g.lda = Dd;
    g.Bm = WpT; g.ldb = Dd;
    g.C = pp; g.ldc = INNER;
    g.M = Bb * L; g.N = INNER; g.K = Dd; g.Hh = 1;
    run_gemm<0, 1, 0>(g, 1, stream);
    g.A = Sbf; g.Bm = WsT; g.C = psb;
    run_gemm<0, 1, 0>(g, 1, stream);
  }

  if (full) {
    GemmP g1{};  // T[b,h] = P_b @ Waff_h
    g1.A = Pbf; g1.lda = Dd; g1.sAb = LD; g1.sAh = 0;
    g1.Bm = WaT; g1.ldb = Dd; g1.sBb = 0; g1.sBh = (long long)Dd * Dd;
    g1.C = Tb; g1.ldc = Dd; g1.sCb = (long long)Hh * LD; g1.sCh = LD;
    g1.M = L; g1.N = Dd; g1.K = Dd; g1.Hh = Hh;
    run_gemm<0, 1, 0>(g1, Bb * Hh, stream);

    GemmP g2{};  // aff[b,h] = tanh(T[b,h] @ S_b^T) * mask
    g2.A = Tb; g2.lda = Dd; g2.sAb = (long long)Hh * LD; g2.sAh = LD;
    g2.Bm = Sbf; g2.ldb = Dd; g2.sBb = LD; g2.sBh = 0;
    g2.C = affb; g2.ldc = L; g2.sCb = (long long)Hh * LL; g2.sCh = LL;
    g2.mask_p = pmask; g2.mask_s = smask;
    g2.M = L; g2.N = L; g2.K = Dd; g2.Hh = Hh;
    run_gemm<0, 1, 1>(g2, Bb * Hh, stream);

    GemmP g4{};  // pool_s max= relu(aff[b,h] @ ps[b][:, h*HD:])
    g4.A = affb; g4.lda = L; g4.sAb = (long long)Hh * LL; g4.sAh = LL;
    g4.Bm = psb; g4.ldb = INNER; g4.sBb = (long long)L * INNER; g4.sBh = HDd;
    g4.C = pool_s; g4.ldc = HDd; g4.sCb = (long long)L * HDd; g4.sCh = 0;
    g4.M = L; g4.N = HDd; g4.K = L; g4.Hh = Hh;
    run_gemm<0, 0, 2>(g4, Bb * Hh, stream);

    GemmP g5 = g4;  // pool_p max= relu(aff[b,h]^T @ pp[b][:, h*HD:])
    g5.Bm = pp;
    g5.C = pool_p;
    run_gemm<1, 0, 2>(g5, Bb * Hh, stream);
  } else {
    for (int h = 0; h < Hh; ++h) {
      GemmP g1{};
      g1.A = Pbf; g1.lda = Dd;
      g1.Bm = WaT + (size_t)h * Dd * Dd; g1.ldb = Dd;
      g1.C = Tb; g1.ldc = Dd;
      g1.M = Bb * L; g1.N = Dd; g1.K = Dd; g1.Hh = 1;
      run_gemm<0, 1, 0>(g1, 1, stream);

      GemmP g2{};
      g2.A = Tb; g2.lda = Dd; g2.sAb = LD;
      g2.Bm = Sbf; g2.ldb = Dd; g2.sBb = LD;
      g2.C = affb; g2.ldc = L; g2.sCb = LL;
      g2.mask_p = pmask; g2.mask_s = smask;
      g2.M = L; g2.N = L; g2.K = Dd; g2.Hh = 1;
      run_gemm<0, 1, 1>(g2, Bb, stream);

      GemmP g4{};
      g4.A = affb; g4.lda = L; g4.sAb = LL;
      g4.Bm = psb + (size_t)h * HDd; g4.ldb = INNER; g4.sBb = (long long)L * INNER;
      g4.C = pool_s; g4.ldc = HDd; g4.sCb = (long long)L * HDd;
      g4.M = L; g4.N = HDd; g4.K = L; g4.Hh = 1;
      run_gemm<0, 0, 2>(g4, Bb, stream);

      GemmP g5 = g4;
      g5.Bm = pp + (size_t)h * HDd;
      g5.C = pool_p;
      run_gemm<1, 0, 2>(g5, Bb, stream);
    }
  }

  // ---- concat + output FFNs ----
  const int catN = Bb * L * CAT;
  concat_k<<<dim3(catN / 256), dim3(256), 0, stream>>>(Pbf, pool_s, catP, Bb * L, Dd, HDd);
  concat_k<<<dim3(catN / 256), dim3(256), 0, stream>>>(Sbf, pool_p, catS, Bb * L, Dd, HDd);

  GemmP g6{};
  g6.A = catP; g6.lda = CAT;
  g6.Bm = WfpT; g6.ldb = CAT;
  g6.C = d_out; g6.ldc = Dd;
  g6.bias = b_fp;
  g6.M = Bb * L; g6.N = Dd; g6.K = CAT; g6.Hh = 1;
  run_gemm<0, 1, 3>(g6, 1, stream);

  g6.A = catS; g6.Bm = WfsT;
  g6.C = (float*)d_out + (size_t)Bb * L * Dd;
  g6.bias = b_fs;
  run_gemm<0, 1, 3>(g6, 1, stream);
}

// Round 2
// 464.678 us; speedup vs baseline: 1.0160x; 1.0160x over previous
//
#include <hip/hip_runtime.h>
#include <hip/hip_bf16.h>

typedef short short8 __attribute__((ext_vector_type(8)));
typedef float f32x4 __attribute__((ext_vector_type(4)));

#define BM 128
#define BN 128
#define BK_ 32

typedef const __attribute__((address_space(1))) void gas_t;
typedef __attribute__((address_space(3))) void las_t;

__device__ __forceinline__ unsigned short f2bf(float f) {
  unsigned int u = __float_as_uint(f);
  u += 0x7FFFu + ((u >> 16) & 1u);   // round-to-nearest-even
  return (unsigned short)(u >> 16);
}

struct GemmP {
  const unsigned short* A;
  const unsigned short* Bm;
  void* C;
  const float* mask_p;
  const float* mask_s;
  const float* bias;
  long long sAb, sAh, sBb, sBh, sCb, sCh;  // batch strides in elements; z -> (zb=z/Hh, zh=z%Hh)
  int lda, ldb, ldc, M, N, K, Hh;
};

// TA: 0 = A is M x K row-major (global_load_lds direct staging, LDS pitch 32, no pad)
//     1 = A stored K x M row-major (VALU transpose staging, LDS pitch 40 padded)
// TB: 1 = B stored N x K row-major (direct staging); 0 = B is K x N row-major (transpose staging)
// EPI: 0 = store bf16; 1 = tanh*mask store bf16; 2 = relu + atomic max into f32 pool; 3 = +bias, relu, store f32
template <int TA, int TB, int EPI>
__global__ __launch_bounds__(256) void gemm_k(GemmP p) {
  constexpr int PA = (TA == 0) ? BK_ : (BK_ + 8);  // direct path must be contiguous for lds-DMA
  constexpr int PB = (TB == 1) ? BK_ : (BK_ + 8);
  __shared__ __align__(16) unsigned short As[BM * PA];
  __shared__ __align__(16) unsigned short Bs[BN * PB];

  const int z = blockIdx.z;
  const int zb = z / p.Hh, zh = z % p.Hh;
  const unsigned short* A = p.A + (size_t)zb * p.sAb + (size_t)zh * p.sAh;
  const unsigned short* B = p.Bm + (size_t)zb * p.sBb + (size_t)zh * p.sBh;
  const int m0 = blockIdx.x * BM, n0 = blockIdx.y * BN;
  const int tid = threadIdx.x;
  const int wid = tid >> 6, lane = tid & 63;
  const int wm = (wid >> 1) * 64, wn = (wid & 1) * 64;
  const int lrow = lane & 15, lkg = lane >> 4;

  f32x4 acc[4][4] = {};

  // direct-staging lane mapping: LDS byte (q*4096 + tid*16) -> row m = q*64 + tid/4, k-group = tid&3
  const int dm = tid >> 2, dkg = tid & 3;

  for (int k0 = 0; k0 < p.K; k0 += BK_) {
    if (TA == 0) {
#pragma unroll
      for (int q = 0; q < 2; ++q) {
        const unsigned short* src = A + (size_t)(m0 + q * 64 + dm) * p.lda + (k0 + dkg * 8);
        __builtin_amdgcn_global_load_lds((gas_t*)src,
                                         (las_t*)&As[q * 2048 + wid * 512],
                                         16, 0, 0);
      }
    } else {
      const int kk = tid & 31, mg = (tid >> 5) << 4;
      const unsigned short* src = A + (size_t)(k0 + kk) * p.lda + (m0 + mg);
      uint4 v0 = *(const uint4*)src;
      uint4 v1 = *(const uint4*)(src + 8);
      unsigned short tmp[16];
      *(uint4*)&tmp[0] = v0;
      *(uint4*)&tmp[8] = v1;
#pragma unroll
      for (int j = 0; j < 16; ++j) As[(mg + j) * PA + kk] = tmp[j];
    }
    if (TB == 1) {
#pragma unroll
      for (int q = 0; q < 2; ++q) {
        const unsigned short* src = B + (size_t)(n0 + q * 64 + dm) * p.ldb + (k0 + dkg * 8);
        __builtin_amdgcn_global_load_lds((gas_t*)src,
                                         (las_t*)&Bs[q * 2048 + wid * 512],
                                         16, 0, 0);
      }
    } else {
      const int kk = tid & 31, ng = (tid >> 5) << 4;
      const unsigned short* src = B + (size_t)(k0 + kk) * p.ldb + (n0 + ng);
      uint4 v0 = *(const uint4*)src;
      uint4 v1 = *(const uint4*)(src + 8);
      unsigned short tmp[16];
      *(uint4*)&tmp[0] = v0;
      *(uint4*)&tmp[8] = v1;
#pragma unroll
      for (int j = 0; j < 16; ++j) Bs[(ng + j) * PB + kk] = tmp[j];
    }
    __syncthreads();

    short8 af[4], bfv[4];
#pragma unroll
    for (int mt = 0; mt < 4; ++mt)
      af[mt] = *(const short8*)&As[(wm + mt * 16 + lrow) * PA + lkg * 8];
#pragma unroll
    for (int nt = 0; nt < 4; ++nt)
      bfv[nt] = *(const short8*)&Bs[(wn + nt * 16 + lrow) * PB + lkg * 8];
#pragma unroll
    for (int mt = 0; mt < 4; ++mt)
#pragma unroll
      for (int nt = 0; nt < 4; ++nt)
        acc[mt][nt] = __builtin_amdgcn_mfma_f32_16x16x32_bf16(af[mt], bfv[nt], acc[mt][nt], 0, 0, 0);
    __syncthreads();
  }

  unsigned short* Cu = (unsigned short*)p.C + (size_t)zb * p.sCb + (size_t)zh * p.sCh;
  float* Cf = (float*)p.C + (size_t)zb * p.sCb + (size_t)zh * p.sCh;

#pragma unroll
  for (int mt = 0; mt < 4; ++mt) {
#pragma unroll
    for (int nt = 0; nt < 4; ++nt) {
      f32x4 a = acc[mt][nt];
#pragma unroll
      for (int r = 0; r < 4; ++r) {
        const int grow = m0 + wm + mt * 16 + lkg * 4 + r;  // C/D: row=(lane>>4)*4+reg
        const int gcol = n0 + wn + nt * 16 + lrow;         //      col=lane&15
        const float v = a[r];
        if constexpr (EPI == 0) {
          Cu[(size_t)grow * p.ldc + gcol] = f2bf(v);
        } else if constexpr (EPI == 1) {
          const float mm = p.mask_p[(size_t)zb * p.M + grow] * p.mask_s[(size_t)zb * p.N + gcol];
          Cu[(size_t)grow * p.ldc + gcol] = f2bf(tanhf(v) * mm);
        } else if constexpr (EPI == 2) {
          // relu output >= 0, pool initialized to 0 -> int compare == float compare
          atomicMax((int*)Cf + (size_t)grow * p.ldc + gcol, __float_as_int(fmaxf(v, 0.f)));
        } else {
          Cf[(size_t)grow * p.ldc + gcol] = fmaxf(v + p.bias[gcol], 0.f);
        }
      }
    }
  }
}

__global__ void cvt_bf16(const float* in, unsigned short* out, int n) {
  int i = blockIdx.x * 256 + threadIdx.x;
  if (i < n) out[i] = f2bf(in[i]);
}

// out[z][c][r] = in[z][r][c]  (fp32 -> bf16, batched transpose)
__global__ void trans_bf16(const float* in, unsigned short* out, int Z, int R, int C) {
  int i = blockIdx.x * 256 + threadIdx.x;
  if (i >= Z * R * C) return;
  int z = i / (R * C), rem = i % (R * C);
  int c = rem / R, r = rem % R;
  out[i] = f2bf(in[(size_t)z * R * C + (size_t)r * C + c]);
}

// out[r][0..D) = X[r][*] (bf16 copy), out[r][D..D+HD) = bf16(pool[r][*])
__global__ void concat_k(const unsigned short* X, const float* pool, unsigned short* out,
                         int rows, int Dd, int HDd) {
  const int W = Dd + HDd;
  int i = blockIdx.x * 256 + threadIdx.x;
  if (i >= rows * W) return;
  int r = i / W, c = i % W;
  out[i] = (c < Dd) ? X[(size_t)r * Dd + c] : f2bf(pool[(size_t)r * HDd + (c - Dd)]);
}

template <int TA, int TB, int EPI>
static inline void run_gemm(const GemmP& q, int Z, hipStream_t stream) {
  dim3 grid(q.M / BM, q.N / BN, Z);
  gemm_k<TA, TB, EPI><<<grid, dim3(256), 0, stream>>>(q);
}

extern "C" void kernel_launch(void* const* d_in, const int* in_sizes, int n_in,
                              void* d_out, int out_size, void* d_ws, size_t ws_size,
                              hipStream_t stream) {
  (void)in_sizes; (void)n_in; (void)out_size;
  const float* primary   = (const float*)d_in[0];
  const float* secondary = (const float*)d_in[1];
  const float* pmask     = (const float*)d_in[2];
  const float* smask     = (const float*)d_in[3];
  const float* W_aff     = (const float*)d_in[4];
  const float* W_p       = (const float*)d_in[5];
  const float* W_s       = (const float*)d_in[6];
  const float* W_fp      = (const float*)d_in[7];
  const float* b_fp      = (const float*)d_in[8];
  const float* W_fs      = (const float*)d_in[9];
  const float* b_fs      = (const float*)d_in[10];

  constexpr int Bb = 16, L = 512, Dd = 512, Hh = 8, HDd = 128, INNER = 1024, CAT = 640;
  constexpr long long LD = (long long)L * Dd;  // 262144
  constexpr long long LL = (long long)L * L;   // 262144

  char* base = (char*)d_ws;
  size_t off = 0;
  auto alloc = [&](size_t bytes) -> void* {
    void* r = base + off;
    off += (bytes + 255) & ~(size_t)255;
    return r;
  };

  unsigned short* Pbf  = (unsigned short*)alloc((size_t)Bb * L * Dd * 2);
  unsigned short* Sbf  = (unsigned short*)alloc((size_t)Bb * L * Dd * 2);
  unsigned short* WaT  = (unsigned short*)alloc((size_t)Hh * Dd * Dd * 2);   // [h][f][e]
  unsigned short* WpT  = (unsigned short*)alloc((size_t)INNER * Dd * 2);     // [n][e]
  unsigned short* WsT  = (unsigned short*)alloc((size_t)INNER * Dd * 2);
  unsigned short* WfpT = (unsigned short*)alloc((size_t)Dd * CAT * 2);       // [n][k]
  unsigned short* WfsT = (unsigned short*)alloc((size_t)Dd * CAT * 2);
  unsigned short* pp   = (unsigned short*)alloc((size_t)Bb * L * INNER * 2); // (B*L1, H*HD)
  unsigned short* psb  = (unsigned short*)alloc((size_t)Bb * L * INNER * 2); // (B*L2, H*HD)
  unsigned short* catP = (unsigned short*)alloc((size_t)Bb * L * CAT * 2);
  unsigned short* catS = (unsigned short*)alloc((size_t)Bb * L * CAT * 2);
  float* pool_p = (float*)alloc((size_t)Bb * L * HDd * 4);
  float* pool_s = (float*)alloc((size_t)Bb * L * HDd * 4);

  const size_t fullT = (size_t)Bb * Hh * L * Dd * 2;  // 64 MiB each for T and aff
  const bool full = (off + 2 * (fullT + 256)) <= ws_size;
  unsigned short* Tb   = (unsigned short*)alloc(full ? fullT : (size_t)Bb * L * Dd * 2);
  unsigned short* affb = (unsigned short*)alloc(full ? fullT : (size_t)Bb * L * L * 2);

  // ---- convert inputs, transpose weights to N x K ----
  {
    const int n = Bb * L * Dd;
    cvt_bf16<<<dim3(n / 256), dim3(256), 0, stream>>>(primary, Pbf, n);
    cvt_bf16<<<dim3(n / 256), dim3(256), 0, stream>>>(secondary, Sbf, n);
  }
  trans_bf16<<<dim3((Hh * Dd * Dd) / 256), dim3(256), 0, stream>>>(W_aff, WaT, Hh, Dd, Dd);
  trans_bf16<<<dim3((Dd * INNER) / 256), dim3(256), 0, stream>>>(W_p, WpT, 1, Dd, INNER);
  trans_bf16<<<dim3((Dd * INNER) / 256), dim3(256), 0, stream>>>(W_s, WsT, 1, Dd, INNER);
  trans_bf16<<<dim3((CAT * Dd) / 256), dim3(256), 0, stream>>>(W_fp, WfpT, 1, CAT, Dd);
  trans_bf16<<<dim3((CAT * Dd) / 256), dim3(256), 0, stream>>>(W_fs, WfsT, 1, CAT, Dd);

  hipMemsetAsync(pool_p, 0, (size_t)Bb * L * HDd * 4, stream);
  hipMemsetAsync(pool_s, 0, (size_t)Bb * L * HDd * 4, stream);

  // ---- pp = P @ W_p ; ps = S @ W_s ----
  {
    GemmP g{};
    g.A = Pbf; g.lda = Dd;
    g.Bm = WpT; g.ldb = Dd;
    g.C = pp; g.ldc = INNER;
    g.M = Bb * L; g.N = INNER; g.K = Dd; g.Hh = 1;
    run_gemm<0, 1, 0>(g, 1, stream);
    g.A = Sbf; g.Bm = WsT; g.C = psb;
    run_gemm<0, 1, 0>(g, 1, stream);
  }

  if (full) {
    GemmP g1{};  // T[b,h] = P_b @ Waff_h
    g1.A = Pbf; g1.lda = Dd; g1.sAb = LD; g1.sAh = 0;
    g1.Bm = WaT; g1.ldb = Dd; g1.sBb = 0; g1.sBh = (long long)Dd * Dd;
    g1.C = Tb; g1.ldc = Dd; g1.sCb = (long long)Hh * LD; g1.sCh = LD;
    g1.M = L; g1.N = Dd; g1.K = Dd; g1.Hh = Hh;
    run_gemm<0, 1, 0>(g1, Bb * Hh, stream);

    GemmP g2{};  // aff[b,h] = tanh(T[b,h] @ S_b^T) * mask
    g2.A = Tb; g2.lda = Dd; g2.sAb = (long long)Hh * LD; g2.sAh = LD;
    g2.Bm = Sbf; g2.ldb = Dd; g2.sBb = LD; g2.sBh = 0;
    g2.C = affb; g2.ldc = L; g2.sCb = (long long)Hh * LL; g2.sCh = LL;
    g2.mask_p = pmask; g2.mask_s = smask;
    g2.M = L; g2.N = L; g2.K = Dd; g2.Hh = Hh;
    run_gemm<0, 1, 1>(g2, Bb * Hh, stream);

    GemmP g4{};  // pool_s max= relu(aff[b,h] @ ps[b][:, h*HD:])
    g4.A = affb; g4.lda = L; g4.sAb = (long long)Hh * LL; g4.sAh = LL;
    g4.Bm = psb; g4.ldb = INNER; g4.sBb = (long long)L * INNER; g4.sBh = HDd;
    g4.C = pool_s; g4.ldc = HDd; g4.sCb = (long long)L * HDd; g4.sCh = 0;
    g4.M = L; g4.N = HDd; g4.K = L; g4.Hh = Hh;
    run_gemm<0, 0, 2>(g4, Bb * Hh, stream);

    GemmP g5 = g4;  // pool_p max= relu(aff[b,h]^T @ pp[b][:, h*HD:])
    g5.Bm = pp;
    g5.C = pool_p;
    run_gemm<1, 0, 2>(g5, Bb * Hh, stream);
  } else {
    for (int h = 0; h < Hh; ++h) {
      GemmP g1{};
      g1.A = Pbf; g1.lda = Dd;
      g1.Bm = WaT + (size_t)h * Dd * Dd; g1.ldb = Dd;
      g1.C = Tb; g1.ldc = Dd;
      g1.M = Bb * L; g1.N = Dd; g1.K = Dd; g1.Hh = 1;
      run_gemm<0, 1, 0>(g1, 1, stream);

      GemmP g2{};
      g2.A = Tb; g2.lda = Dd; g2.sAb = LD;
      g2.Bm = Sbf; g2.ldb = Dd; g2.sBb = LD;
      g2.C = affb; g2.ldc = L; g2.sCb = LL;
      g2.mask_p = pmask; g2.mask_s = smask;
      g2.M = L; g2.N = L; g2.K = Dd; g2.Hh = 1;
      run_gemm<0, 1, 1>(g2, Bb, stream);

      GemmP g4{};
      g4.A = affb; g4.lda = L; g4.sAb = LL;
      g4.Bm = psb + (size_t)h * HDd; g4.ldb = INNER; g4.sBb = (long long)L * INNER;
      g4.C = pool_s; g4.ldc = HDd; g4.sCb = (long long)L * HDd;
      g4.M = L; g4.N = HDd; g4.K = L; g4.Hh = 1;
      run_gemm<0, 0, 2>(g4, Bb, stream);

      GemmP g5 = g4;
      g5.Bm = pp + (size_t)h * HDd;
      g5.C = pool_p;
      run_gemm<1, 0, 2>(g5, Bb, stream);
    }
  }

  // ---- concat + output FFNs ----
  const int catN = Bb * L * CAT;
  concat_k<<<dim3(catN / 256), dim3(256), 0, stream>>>(Pbf, pool_s, catP, Bb * L, Dd, HDd);
  concat_k<<<dim3(catN / 256), dim3(256), 0, stream>>>(Sbf, pool_p, catS, Bb * L, Dd, HDd);

  GemmP g6{};
  g6.A = catP; g6.lda = CAT;
  g6.Bm = WfpT; g6.ldb = CAT;
  g6.C = d_out; g6.ldc = Dd;
  g6.bias = b_fp;
  g6.M = Bb * L; g6.N = Dd; g6.K = CAT; g6.Hh = 1;
  run_gemm<0, 1, 3>(g6, 1, stream);

  g6.A = catS; g6.Bm = WfsT;
  g6.C = (float*)d_out + (size_t)Bb * L * Dd;
  g6.bias = b_fs;
  run_gemm<0, 1, 3>(g6, 1, stream);
}

// Round 3
// 408.282 us; speedup vs baseline: 1.1564x; 1.1381x over previous
//
#include <hip/hip_runtime.h>
#include <hip/hip_bf16.h>

typedef short short8 __attribute__((ext_vector_type(8)));
typedef float f32x4 __attribute__((ext_vector_type(4)));

#define BM 128
#define BN 128

typedef const __attribute__((address_space(1))) void gas_t;
typedef __attribute__((address_space(3))) void las_t;

__device__ __forceinline__ unsigned short f2bf(float f) {
  unsigned int u = __float_as_uint(f);
  u += 0x7FFFu + ((u >> 16) & 1u);   // round-to-nearest-even
  return (unsigned short)(u >> 16);
}

// tanh via single v_exp_f32 + v_rcp_f32: tanh(x) = (e^2x - 1)/(e^2x + 1).
// Clamp to +-10 (tanh(10) == 1.0 in bf16) to avoid inf/inf -> NaN.
__device__ __forceinline__ float fast_tanh(float x) {
  x = fminf(fmaxf(x, -10.f), 10.f);
  float t = __builtin_amdgcn_exp2f(x * 2.8853900817779268f);  // 2*log2(e)
  return (t - 1.f) * __builtin_amdgcn_rcpf(t + 1.f);
}

struct GemmP {
  const unsigned short* A;
  const unsigned short* Bm;
  void* C;
  const float* mask_p;
  const float* mask_s;
  const float* bias;
  long long sAb, sAh, sBb, sBh, sCb, sCh;  // batch strides in elements; z -> (zb=z/Hh, zh=z%Hh)
  int lda, ldb, ldc, M, N, K, Hh;
};

// TA: 0 = A is M x K row-major (global_load_lds direct staging, LDS pitch 32, no pad)
//     1 = A stored K x M row-major (VALU transpose staging, LDS pitch 40 padded)
// TB: 1 = B stored N x K row-major (direct staging); 0 = B is K x N row-major (transpose staging)
// EPI: 0 = store bf16; 1 = tanh*mask store bf16; 2 = relu + atomic max into f32 pool; 3 = +bias, relu, store f32
// K-loop: BK=64 as two BK=32 half-tiles (keeps m97's proven pitch-32 LDS layout & lds-DMA mapping,
// halves the barrier count for short-K amortization).
template <int TA, int TB, int EPI>
__global__ __launch_bounds__(256) void gemm_k(GemmP p) {
  constexpr int PA = (TA == 0) ? 32 : 40;
  constexpr int PB = (TB == 1) ? 32 : 40;
  constexpr int HSA = (TA == 0) ? 4096 : 5120;  // shorts per half-tile
  constexpr int HSB = (TB == 1) ? 4096 : 5120;
  __shared__ __align__(16) unsigned short As[2 * HSA];
  __shared__ __align__(16) unsigned short Bs[2 * HSB];

  const int z = blockIdx.z;
  const int zb = z / p.Hh, zh = z % p.Hh;
  const unsigned short* A = p.A + (size_t)zb * p.sAb + (size_t)zh * p.sAh;
  const unsigned short* B = p.Bm + (size_t)zb * p.sBb + (size_t)zh * p.sBh;
  const int m0 = blockIdx.x * BM, n0 = blockIdx.y * BN;
  const int tid = threadIdx.x;
  const int wid = tid >> 6, lane = tid & 63;
  const int wm = (wid >> 1) * 64, wn = (wid & 1) * 64;
  const int lrow = lane & 15, lkg = lane >> 4;

  f32x4 acc[4][4] = {};

  // direct-staging lane mapping: LDS byte (q*4096 + tid*16) -> row m = q*64 + tid/4, k-group = tid&3
  const int dm = tid >> 2, dkg = tid & 3;

  for (int k0 = 0; k0 < p.K; k0 += 64) {
    if (TA == 0) {
#pragma unroll
      for (int h = 0; h < 2; ++h)
#pragma unroll
        for (int q = 0; q < 2; ++q) {
          const unsigned short* src =
              A + (size_t)(m0 + q * 64 + dm) * p.lda + (k0 + h * 32 + dkg * 8);
          __builtin_amdgcn_global_load_lds((gas_t*)src,
                                           (las_t*)&As[h * HSA + q * 2048 + wid * 512],
                                           16, 0, 0);
        }
    } else {
      const int kk = tid & 31, mg = (tid >> 5) << 4;
#pragma unroll
      for (int h = 0; h < 2; ++h) {
        const unsigned short* src = A + (size_t)(k0 + h * 32 + kk) * p.lda + (m0 + mg);
        uint4 v0 = *(const uint4*)src;
        uint4 v1 = *(const uint4*)(src + 8);
        unsigned short tmp[16];
        *(uint4*)&tmp[0] = v0;
        *(uint4*)&tmp[8] = v1;
#pragma unroll
        for (int j = 0; j < 16; ++j) As[h * HSA + (mg + j) * PA + kk] = tmp[j];
      }
    }
    if (TB == 1) {
#pragma unroll
      for (int h = 0; h < 2; ++h)
#pragma unroll
        for (int q = 0; q < 2; ++q) {
          const unsigned short* src =
              B + (size_t)(n0 + q * 64 + dm) * p.ldb + (k0 + h * 32 + dkg * 8);
          __builtin_amdgcn_global_load_lds((gas_t*)src,
                                           (las_t*)&Bs[h * HSB + q * 2048 + wid * 512],
                                           16, 0, 0);
        }
    } else {
      const int kk = tid & 31, ng = (tid >> 5) << 4;
#pragma unroll
      for (int h = 0; h < 2; ++h) {
        const unsigned short* src = B + (size_t)(k0 + h * 32 + kk) * p.ldb + (n0 + ng);
        uint4 v0 = *(const uint4*)src;
        uint4 v1 = *(const uint4*)(src + 8);
        unsigned short tmp[16];
        *(uint4*)&tmp[0] = v0;
        *(uint4*)&tmp[8] = v1;
#pragma unroll
        for (int j = 0; j < 16; ++j) Bs[h * HSB + (ng + j) * PB + kk] = tmp[j];
      }
    }
    __syncthreads();

#pragma unroll
    for (int h = 0; h < 2; ++h) {
      short8 af[4], bfv[4];
#pragma unroll
      for (int mt = 0; mt < 4; ++mt)
        af[mt] = *(const short8*)&As[h * HSA + (wm + mt * 16 + lrow) * PA + lkg * 8];
#pragma unroll
      for (int nt = 0; nt < 4; ++nt)
        bfv[nt] = *(const short8*)&Bs[h * HSB + (wn + nt * 16 + lrow) * PB + lkg * 8];
#pragma unroll
      for (int mt = 0; mt < 4; ++mt)
#pragma unroll
        for (int nt = 0; nt < 4; ++nt)
          acc[mt][nt] = __builtin_amdgcn_mfma_f32_16x16x32_bf16(af[mt], bfv[nt], acc[mt][nt], 0, 0, 0);
    }
    __syncthreads();
  }

  unsigned short* Cu = (unsigned short*)p.C + (size_t)zb * p.sCb + (size_t)zh * p.sCh;
  float* Cf = (float*)p.C + (size_t)zb * p.sCb + (size_t)zh * p.sCh;

#pragma unroll
  for (int mt = 0; mt < 4; ++mt) {
#pragma unroll
    for (int nt = 0; nt < 4; ++nt) {
      f32x4 a = acc[mt][nt];
#pragma unroll
      for (int r = 0; r < 4; ++r) {
        const int grow = m0 + wm + mt * 16 + lkg * 4 + r;  // C/D: row=(lane>>4)*4+reg
        const int gcol = n0 + wn + nt * 16 + lrow;         //      col=lane&15
        const float v = a[r];
        if constexpr (EPI == 0) {
          Cu[(size_t)grow * p.ldc + gcol] = f2bf(v);
        } else if constexpr (EPI == 1) {
          const float mm = p.mask_p[(size_t)zb * p.M + grow] * p.mask_s[(size_t)zb * p.N + gcol];
          Cu[(size_t)grow * p.ldc + gcol] = f2bf(fast_tanh(v) * mm);
        } else if constexpr (EPI == 2) {
          // relu output >= 0, pool initialized to 0 -> int compare == float compare
          atomicMax((int*)Cf + (size_t)grow * p.ldc + gcol, __float_as_int(fmaxf(v, 0.f)));
        } else {
          Cf[(size_t)grow * p.ldc + gcol] = fmaxf(v + p.bias[gcol], 0.f);
        }
      }
    }
  }
}

__global__ void cvt_bf16_v4(const float4* in, ushort4* out, int n4) {
  int i = blockIdx.x * 256 + threadIdx.x;
  if (i >= n4) return;
  float4 v = in[i];
  ushort4 o;
  o.x = f2bf(v.x); o.y = f2bf(v.y); o.z = f2bf(v.z); o.w = f2bf(v.w);
  out[i] = o;
}

// out[z][c][r] = in[z][r][c]  (fp32 -> bf16, LDS-tiled transpose, 32x32 tiles)
__global__ __launch_bounds__(256) void trans_bf16(const float* in, unsigned short* out,
                                                  int R, int C) {
  __shared__ float tile[32][33];
  const int z = blockIdx.z;
  const int r0 = blockIdx.y * 32, c0 = blockIdx.x * 32;
  const int tx = threadIdx.x & 31, ty = threadIdx.x >> 5;  // 32 x 8
  const float* src = in + (size_t)z * R * C;
  unsigned short* dst = out + (size_t)z * R * C;
#pragma unroll
  for (int j = 0; j < 4; ++j)
    tile[ty + j * 8][tx] = src[(size_t)(r0 + ty + j * 8) * C + (c0 + tx)];
  __syncthreads();
#pragma unroll
  for (int j = 0; j < 4; ++j)
    dst[(size_t)(c0 + ty + j * 8) * R + (r0 + tx)] = f2bf(tile[tx][ty + j * 8]);
}

// out[r][0..D) = X[r][*] (bf16 copy), out[r][D..D+HD) = bf16(pool[r][*])
__global__ void concat_k(const unsigned short* X, const float* pool, unsigned short* out,
                         int rows, int Dd, int HDd) {
  const int W = Dd + HDd;
  int i = blockIdx.x * 256 + threadIdx.x;
  if (i >= rows * W) return;
  int r = i / W, c = i % W;
  out[i] = (c < Dd) ? X[(size_t)r * Dd + c] : f2bf(pool[(size_t)r * HDd + (c - Dd)]);
}

template <int TA, int TB, int EPI>
static inline void run_gemm(const GemmP& q, int Z, hipStream_t stream) {
  dim3 grid(q.M / BM, q.N / BN, Z);
  gemm_k<TA, TB, EPI><<<grid, dim3(256), 0, stream>>>(q);
}

extern "C" void kernel_launch(void* const* d_in, const int* in_sizes, int n_in,
                              void* d_out, int out_size, void* d_ws, size_t ws_size,
                              hipStream_t stream) {
  (void)in_sizes; (void)n_in; (void)out_size;
  const float* primary   = (const float*)d_in[0];
  const float* secondary = (const float*)d_in[1];
  const float* pmask     = (const float*)d_in[2];
  const float* smask     = (const float*)d_in[3];
  const float* W_aff     = (const float*)d_in[4];
  const float* W_p       = (const float*)d_in[5];
  const float* W_s       = (const float*)d_in[6];
  const float* W_fp      = (const float*)d_in[7];
  const float* b_fp      = (const float*)d_in[8];
  const float* W_fs      = (const float*)d_in[9];
  const float* b_fs      = (const float*)d_in[10];

  constexpr int Bb = 16, L = 512, Dd = 512, Hh = 8, HDd = 128, INNER = 1024, CAT = 640;
  constexpr long long LD = (long long)L * Dd;  // 262144
  constexpr long long LL = (long long)L * L;   // 262144

  char* base = (char*)d_ws;
  size_t off = 0;
  auto alloc = [&](size_t bytes) -> void* {
    void* r = base + off;
    off += (bytes + 255) & ~(size_t)255;
    return r;
  };

  unsigned short* Pbf  = (unsigned short*)alloc((size_t)Bb * L * Dd * 2);
  unsigned short* Sbf  = (unsigned short*)alloc((size_t)Bb * L * Dd * 2);
  unsigned short* WaT  = (unsigned short*)alloc((size_t)Hh * Dd * Dd * 2);   // [h][f][e]
  unsigned short* WpT  = (unsigned short*)alloc((size_t)INNER * Dd * 2);     // [n][e]
  unsigned short* WsT  = (unsigned short*)alloc((size_t)INNER * Dd * 2);
  unsigned short* WfpT = (unsigned short*)alloc((size_t)Dd * CAT * 2);       // [n][k]
  unsigned short* WfsT = (unsigned short*)alloc((size_t)Dd * CAT * 2);
  unsigned short* pp   = (unsigned short*)alloc((size_t)Bb * L * INNER * 2); // (B*L1, H*HD)
  unsigned short* psb  = (unsigned short*)alloc((size_t)Bb * L * INNER * 2); // (B*L2, H*HD)
  unsigned short* catP = (unsigned short*)alloc((size_t)Bb * L * CAT * 2);
  unsigned short* catS = (unsigned short*)alloc((size_t)Bb * L * CAT * 2);
  float* pool_p = (float*)alloc((size_t)Bb * L * HDd * 4);
  float* pool_s = (float*)alloc((size_t)Bb * L * HDd * 4);

  const size_t fullT = (size_t)Bb * Hh * L * Dd * 2;  // 64 MiB each for T and aff
  const bool full = (off + 2 * (fullT + 256)) <= ws_size;
  unsigned short* Tb   = (unsigned short*)alloc(full ? fullT : (size_t)Bb * L * Dd * 2);
  unsigned short* affb = (unsigned short*)alloc(full ? fullT : (size_t)Bb * L * L * 2);

  // ---- convert inputs, transpose weights to N x K ----
  {
    const int n4 = (Bb * L * Dd) / 4;
    cvt_bf16_v4<<<dim3((n4 + 255) / 256), dim3(256), 0, stream>>>((const float4*)primary, (ushort4*)Pbf, n4);
    cvt_bf16_v4<<<dim3((n4 + 255) / 256), dim3(256), 0, stream>>>((const float4*)secondary, (ushort4*)Sbf, n4);
  }
  trans_bf16<<<dim3(Dd / 32, Dd / 32, Hh), dim3(256), 0, stream>>>(W_aff, WaT, Dd, Dd);
  trans_bf16<<<dim3(INNER / 32, Dd / 32, 1), dim3(256), 0, stream>>>(W_p, WpT, Dd, INNER);
  trans_bf16<<<dim3(INNER / 32, Dd / 32, 1), dim3(256), 0, stream>>>(W_s, WsT, Dd, INNER);
  trans_bf16<<<dim3(Dd / 32, CAT / 32, 1), dim3(256), 0, stream>>>(W_fp, WfpT, CAT, Dd);
  trans_bf16<<<dim3(Dd / 32, CAT / 32, 1), dim3(256), 0, stream>>>(W_fs, WfsT, CAT, Dd);

  hipMemsetAsync(pool_p, 0, (size_t)Bb * L * HDd * 4, stream);
  hipMemsetAsync(pool_s, 0, (size_t)Bb * L * HDd * 4, stream);

  // ---- pp = P @ W_p ; ps = S @ W_s ----
  {
    GemmP g{};
    g.A = Pbf; g.lda = Dd;
    g.Bm = WpT; g.ldb = Dd;
    g.C = pp; g.ldc = INNER;
    g.M = Bb * L; g.N = INNER; g.K = Dd; g.Hh = 1;
    run_gemm<0, 1, 0>(g, 1, stream);
    g.A = Sbf; g.Bm = WsT; g.C = psb;
    run_gemm<0, 1, 0>(g, 1, stream);
  }

  if (full) {
    GemmP g1{};  // T[b,h] = P_b @ Waff_h
    g1.A = Pbf; g1.lda = Dd; g1.sAb = LD; g1.sAh = 0;
    g1.Bm = WaT; g1.ldb = Dd; g1.sBb = 0; g1.sBh = (long long)Dd * Dd;
    g1.C = Tb; g1.ldc = Dd; g1.sCb = (long long)Hh * LD; g1.sCh = LD;
    g1.M = L; g1.N = Dd; g1.K = Dd; g1.Hh = Hh;
    run_gemm<0, 1, 0>(g1, Bb * Hh, stream);

    GemmP g2{};  // aff[b,h] = tanh(T[b,h] @ S_b^T) * mask
    g2.A = Tb; g2.lda = Dd; g2.sAb = (long long)Hh * LD; g2.sAh = LD;
    g2.Bm = Sbf; g2.ldb = Dd; g2.sBb = LD; g2.sBh = 0;
    g2.C = affb; g2.ldc = L; g2.sCb = (long long)Hh * LL; g2.sCh = LL;
    g2.mask_p = pmask; g2.mask_s = smask;
    g2.M = L; g2.N = L; g2.K = Dd; g2.Hh = Hh;
    run_gemm<0, 1, 1>(g2, Bb * Hh, stream);

    GemmP g4{};  // pool_s max= relu(aff[b,h] @ ps[b][:, h*HD:])
    g4.A = affb; g4.lda = L; g4.sAb = (long long)Hh * LL; g4.sAh = LL;
    g4.Bm = psb; g4.ldb = INNER; g4.sBb = (long long)L * INNER; g4.sBh = HDd;
    g4.C = pool_s; g4.ldc = HDd; g4.sCb = (long long)L * HDd; g4.sCh = 0;
    g4.M = L; g4.N = HDd; g4.K = L; g4.Hh = Hh;
    run_gemm<0, 0, 2>(g4, Bb * Hh, stream);

    GemmP g5 = g4;  // pool_p max= relu(aff[b,h]^T @ pp[b][:, h*HD:])
    g5.Bm = pp;
    g5.C = pool_p;
    run_gemm<1, 0, 2>(g5, Bb * Hh, stream);
  } else {
    for (int h = 0; h < Hh; ++h) {
      GemmP g1{};
      g1.A = Pbf; g1.lda = Dd;
      g1.Bm = WaT + (size_t)h * Dd * Dd; g1.ldb = Dd;
      g1.C = Tb; g1.ldc = Dd;
      g1.M = Bb * L; g1.N = Dd; g1.K = Dd; g1.Hh = 1;
      run_gemm<0, 1, 0>(g1, 1, stream);

      GemmP g2{};
      g2.A = Tb; g2.lda = Dd; g2.sAb = LD;
      g2.Bm = Sbf; g2.ldb = Dd; g2.sBb = LD;
      g2.C = affb; g2.ldc = L; g2.sCb = LL;
      g2.mask_p = pmask; g2.mask_s = smask;
      g2.M = L; g2.N = L; g2.K = Dd; g2.Hh = 1;
      run_gemm<0, 1, 1>(g2, Bb, stream);

      GemmP g4{};
      g4.A = affb; g4.lda = L; g4.sAb = LL;
      g4.Bm = psb + (size_t)h * HDd; g4.ldb = INNER; g4.sBb = (long long)L * INNER;
      g4.C = pool_s; g4.ldc = HDd; g4.sCb = (long long)L * HDd;
      g4.M = L; g4.N = HDd; g4.K = L; g4.Hh = 1;
      run_gemm<0, 0, 2>(g4, Bb, stream);

      GemmP g5 = g4;
      g5.Bm = pp + (size_t)h * HDd;
      g5.C = pool_p;
      run_gemm<1, 0, 2>(g5, Bb, stream);
    }
  }

  // ---- concat + output FFNs ----
  const int catN = Bb * L * CAT;
  concat_k<<<dim3(catN / 256), dim3(256), 0, stream>>>(Pbf, pool_s, catP, Bb * L, Dd, HDd);
  concat_k<<<dim3(catN / 256), dim3(256), 0, stream>>>(Sbf, pool_p, catS, Bb * L, Dd, HDd);

  GemmP g6{};
  g6.A = catP; g6.lda = CAT;
  g6.Bm = WfpT; g6.ldb = CAT;
  g6.C = d_out; g6.ldc = Dd;
  g6.bias = b_fp;
  g6.M = Bb * L; g6.N = Dd; g6.K = CAT; g6.Hh = 1;
  run_gemm<0, 1, 3>(g6, 1, stream);

  g6.A = catS; g6.Bm = WfsT;
  g6.C = (float*)d_out + (size_t)Bb * L * Dd;
  g6.bias = b_fs;
  run_gemm<0, 1, 3>(g6, 1, stream);
}

// Round 4
// 380.471 us; speedup vs baseline: 1.2409x; 1.0731x over previous
//
#include <hip/hip_runtime.h>
#include <hip/hip_bf16.h>

typedef short short8 __attribute__((ext_vector_type(8)));
typedef float f32x4 __attribute__((ext_vector_type(4)));

#define BM 128
#define BN 128

typedef const __attribute__((address_space(1))) void gas_t;
typedef __attribute__((address_space(3))) void las_t;

__device__ __forceinline__ unsigned short f2bf(float f) {
  unsigned int u = __float_as_uint(f);
  u += 0x7FFFu + ((u >> 16) & 1u);   // round-to-nearest-even
  return (unsigned short)(u >> 16);
}

// tanh via single v_exp_f32 + v_rcp_f32: tanh(x) = 1 - 2/(e^2x + 1).
// Clamp to +-10 (tanh(10) == 1.0 in bf16) to avoid inf/inf -> NaN.
__device__ __forceinline__ float fast_tanh(float x) {
  x = fminf(fmaxf(x, -10.f), 10.f);
  float t = __builtin_amdgcn_exp2f(x * 2.8853900817779268f);  // 2*log2(e)
  return 1.f - 2.f * __builtin_amdgcn_rcpf(t + 1.f);
}

struct GemmP {
  const unsigned short* A;
  const unsigned short* A2;   // second A source for k >= kSplit (piecewise concat rows)
  const unsigned short* Bm;
  void* C;
  const float* mask_p;
  const float* mask_s;
  const float* bias;
  long long sAb, sAh, sBb, sBh, sCb, sCh;  // batch strides in elements; z -> (zb=z/Hh, zh=z%Hh)
  int lda, lda2, ldb, ldc, M, N, K, Hh, kSplit;  // kSplit=0 -> A2 disabled
};

// TA: 0 = A is M x K row-major (global_load_lds direct staging, LDS pitch 32, no pad)
//     1 = A stored K x M row-major (VALU transpose staging, LDS pitch 40 padded)
// TB: 1 = B stored N x K row-major (direct staging); 0 = B is K x N row-major (transpose staging)
// EPI: 0 = store bf16; 1 = tanh*mask store bf16; 2 = relu + atomic max into f32 pool; 3 = +bias, relu, store f32
// K-loop: BK=64 as two BK=32 half-tiles (keeps m97's proven pitch-32 LDS layout & lds-DMA mapping).
template <int TA, int TB, int EPI>
__global__ __launch_bounds__(256) void gemm_k(GemmP p) {
  constexpr int PA = (TA == 0) ? 32 : 40;
  constexpr int PB = (TB == 1) ? 32 : 40;
  constexpr int HSA = (TA == 0) ? 4096 : 5120;  // shorts per half-tile
  constexpr int HSB = (TB == 1) ? 4096 : 5120;
  __shared__ __align__(16) unsigned short As[2 * HSA];
  __shared__ __align__(16) unsigned short Bs[2 * HSB];

  const int z = blockIdx.z;
  const int zb = z / p.Hh, zh = z % p.Hh;
  const unsigned short* A = p.A + (size_t)zb * p.sAb + (size_t)zh * p.sAh;
  const unsigned short* B = p.Bm + (size_t)zb * p.sBb + (size_t)zh * p.sBh;
  const int m0 = blockIdx.x * BM, n0 = blockIdx.y * BN;
  const int tid = threadIdx.x;
  const int wid = tid >> 6, lane = tid & 63;
  const int wm = (wid >> 1) * 64, wn = (wid & 1) * 64;
  const int lrow = lane & 15, lkg = lane >> 4;

  f32x4 acc[4][4] = {};

  // direct-staging lane mapping: LDS byte (q*4096 + tid*16) -> row m = q*64 + tid/4, k-group = tid&3
  const int dm = tid >> 2, dkg = tid & 3;

  for (int k0 = 0; k0 < p.K; k0 += 64) {
    if (TA == 0) {
#pragma unroll
      for (int h = 0; h < 2; ++h) {
        const int kk = k0 + h * 32;  // 32-wide half-tile is entirely on one side of kSplit
        const unsigned short* Ab = A;
        int al = p.lda, ko = kk;
        if (p.kSplit && kk >= p.kSplit) { Ab = p.A2; al = p.lda2; ko = kk - p.kSplit; }
#pragma unroll
        for (int q = 0; q < 2; ++q) {
          const unsigned short* src = Ab + (size_t)(m0 + q * 64 + dm) * al + (ko + dkg * 8);
          __builtin_amdgcn_global_load_lds((gas_t*)src,
                                           (las_t*)&As[h * HSA + q * 2048 + wid * 512],
                                           16, 0, 0);
        }
      }
    } else {
      const int kk = tid & 31, mg = (tid >> 5) << 4;
#pragma unroll
      for (int h = 0; h < 2; ++h) {
        const unsigned short* src = A + (size_t)(k0 + h * 32 + kk) * p.lda + (m0 + mg);
        uint4 v0 = *(const uint4*)src;
        uint4 v1 = *(const uint4*)(src + 8);
        unsigned short tmp[16];
        *(uint4*)&tmp[0] = v0;
        *(uint4*)&tmp[8] = v1;
#pragma unroll
        for (int j = 0; j < 16; ++j) As[h * HSA + (mg + j) * PA + kk] = tmp[j];
      }
    }
    if (TB == 1) {
#pragma unroll
      for (int h = 0; h < 2; ++h)
#pragma unroll
        for (int q = 0; q < 2; ++q) {
          const unsigned short* src =
              B + (size_t)(n0 + q * 64 + dm) * p.ldb + (k0 + h * 32 + dkg * 8);
          __builtin_amdgcn_global_load_lds((gas_t*)src,
                                           (las_t*)&Bs[h * HSB + q * 2048 + wid * 512],
                                           16, 0, 0);
        }
    } else {
      const int kk = tid & 31, ng = (tid >> 5) << 4;
#pragma unroll
      for (int h = 0; h < 2; ++h) {
        const unsigned short* src = B + (size_t)(k0 + h * 32 + kk) * p.ldb + (n0 + ng);
        uint4 v0 = *(const uint4*)src;
        uint4 v1 = *(const uint4*)(src + 8);
        unsigned short tmp[16];
        *(uint4*)&tmp[0] = v0;
        *(uint4*)&tmp[8] = v1;
#pragma unroll
        for (int j = 0; j < 16; ++j) Bs[h * HSB + (ng + j) * PB + kk] = tmp[j];
      }
    }
    __syncthreads();

#pragma unroll
    for (int h = 0; h < 2; ++h) {
      short8 af[4], bfv[4];
#pragma unroll
      for (int mt = 0; mt < 4; ++mt)
        af[mt] = *(const short8*)&As[h * HSA + (wm + mt * 16 + lrow) * PA + lkg * 8];
#pragma unroll
      for (int nt = 0; nt < 4; ++nt)
        bfv[nt] = *(const short8*)&Bs[h * HSB + (wn + nt * 16 + lrow) * PB + lkg * 8];
#pragma unroll
      for (int mt = 0; mt < 4; ++mt)
#pragma unroll
        for (int nt = 0; nt < 4; ++nt)
          acc[mt][nt] = __builtin_amdgcn_mfma_f32_16x16x32_bf16(af[mt], bfv[nt], acc[mt][nt], 0, 0, 0);
    }
    __syncthreads();
  }

  unsigned short* Cu = (unsigned short*)p.C + (size_t)zb * p.sCb + (size_t)zh * p.sCh;
  float* Cf = (float*)p.C + (size_t)zb * p.sCb + (size_t)zh * p.sCh;

  // hoisted epilogue operands (16 row values, 4 col values) -- replaces per-element global loads
  float mp[16], ms[4];
  if constexpr (EPI == 1) {
#pragma unroll
    for (int mt = 0; mt < 4; ++mt)
#pragma unroll
      for (int r = 0; r < 4; ++r)
        mp[mt * 4 + r] = p.mask_p[(size_t)zb * p.M + (m0 + wm + mt * 16 + lkg * 4 + r)];
#pragma unroll
    for (int nt = 0; nt < 4; ++nt)
      ms[nt] = p.mask_s[(size_t)zb * p.N + (n0 + wn + nt * 16 + lrow)];
  }
  if constexpr (EPI == 3) {
#pragma unroll
    for (int nt = 0; nt < 4; ++nt)
      ms[nt] = p.bias[n0 + wn + nt * 16 + lrow];
  }

#pragma unroll
  for (int mt = 0; mt < 4; ++mt) {
#pragma unroll
    for (int nt = 0; nt < 4; ++nt) {
      f32x4 a = acc[mt][nt];
#pragma unroll
      for (int r = 0; r < 4; ++r) {
        const int grow = m0 + wm + mt * 16 + lkg * 4 + r;  // C/D: row=(lane>>4)*4+reg
        const int gcol = n0 + wn + nt * 16 + lrow;         //      col=lane&15
        const float v = a[r];
        if constexpr (EPI == 0) {
          Cu[(size_t)grow * p.ldc + gcol] = f2bf(v);
        } else if constexpr (EPI == 1) {
          Cu[(size_t)grow * p.ldc + gcol] = f2bf(fast_tanh(v) * (mp[mt * 4 + r] * ms[nt]));
        } else if constexpr (EPI == 2) {
          // relu output >= 0, pool initialized to 0 -> int compare == float compare
          atomicMax((int*)Cf + (size_t)grow * p.ldc + gcol, __float_as_int(fmaxf(v, 0.f)));
        } else {
          Cf[(size_t)grow * p.ldc + gcol] = fmaxf(v + ms[nt], 0.f);
        }
      }
    }
  }
}

__global__ void cvt_bf16_v4(const float4* in, ushort4* out, int n4) {
  int i = blockIdx.x * 256 + threadIdx.x;
  if (i >= n4) return;
  float4 v = in[i];
  ushort4 o;
  o.x = f2bf(v.x); o.y = f2bf(v.y); o.z = f2bf(v.z); o.w = f2bf(v.w);
  out[i] = o;
}

// out[z][c][r] = in[z][r][c]  (fp32 -> bf16, LDS-tiled transpose, 32x32 tiles)
__global__ __launch_bounds__(256) void trans_bf16(const float* in, unsigned short* out,
                                                  int R, int C) {
  __shared__ float tile[32][33];
  const int z = blockIdx.z;
  const int r0 = blockIdx.y * 32, c0 = blockIdx.x * 32;
  const int tx = threadIdx.x & 31, ty = threadIdx.x >> 5;  // 32 x 8
  const float* src = in + (size_t)z * R * C;
  unsigned short* dst = out + (size_t)z * R * C;
#pragma unroll
  for (int j = 0; j < 4; ++j)
    tile[ty + j * 8][tx] = src[(size_t)(r0 + ty + j * 8) * C + (c0 + tx)];
  __syncthreads();
#pragma unroll
  for (int j = 0; j < 4; ++j)
    dst[(size_t)(c0 + ty + j * 8) * R + (r0 + tx)] = f2bf(tile[tx][ty + j * 8]);
}

template <int TA, int TB, int EPI>
static inline void run_gemm(const GemmP& q, int Z, hipStream_t stream) {
  dim3 grid(q.M / BM, q.N / BN, Z);
  gemm_k<TA, TB, EPI><<<grid, dim3(256), 0, stream>>>(q);
}

extern "C" void kernel_launch(void* const* d_in, const int* in_sizes, int n_in,
                              void* d_out, int out_size, void* d_ws, size_t ws_size,
                              hipStream_t stream) {
  (void)in_sizes; (void)n_in; (void)out_size; (void)ws_size;
  const float* primary   = (const float*)d_in[0];
  const float* secondary = (const float*)d_in[1];
  const float* pmask     = (const float*)d_in[2];
  const float* smask     = (const float*)d_in[3];
  const float* W_aff     = (const float*)d_in[4];
  const float* W_p       = (const float*)d_in[5];
  const float* W_s       = (const float*)d_in[6];
  const float* W_fp      = (const float*)d_in[7];
  const float* b_fp      = (const float*)d_in[8];
  const float* W_fs      = (const float*)d_in[9];
  const float* b_fs      = (const float*)d_in[10];

  constexpr int Bb = 16, L = 512, Dd = 512, Hh = 8, HDd = 128, INNER = 1024, CAT = 640;
  constexpr int NW = Hh * Dd + INNER;              // 5120: [W_aff heads | W_p] stacked N
  constexpr long long LD = (long long)L * Dd;      // 262144
  constexpr long long LL = (long long)L * L;       // 262144

  char* base = (char*)d_ws;
  size_t off = 0;
  auto alloc = [&](size_t bytes) -> void* {
    void* r = base + off;
    off += (bytes + 255) & ~(size_t)255;
    return r;
  };

  unsigned short* Pbf   = (unsigned short*)alloc((size_t)Bb * L * Dd * 2);
  unsigned short* Sbf   = (unsigned short*)alloc((size_t)Bb * L * Dd * 2);
  unsigned short* Wcomb = (unsigned short*)alloc((size_t)NW * Dd * 2);        // [Waff^T heads | Wp^T], N x K
  unsigned short* WsT   = (unsigned short*)alloc((size_t)INNER * Dd * 2);     // [n][e]
  unsigned short* WfpT  = (unsigned short*)alloc((size_t)Dd * CAT * 2);       // [n][k]
  unsigned short* WfsT  = (unsigned short*)alloc((size_t)Dd * CAT * 2);
  unsigned short* psb   = (unsigned short*)alloc((size_t)Bb * L * INNER * 2); // (B*L2, H*HD)
  unsigned short* wideC = (unsigned short*)alloc((size_t)Bb * L * NW * 2);    // [b*L+i][T(4096) | pp(1024)]
  unsigned short* affb  = (unsigned short*)alloc((size_t)Bb * Hh * L * L * 2);
  float* pool_p = (float*)alloc((size_t)Bb * L * HDd * 4);
  float* pool_s = (float*)alloc((size_t)Bb * L * HDd * 4);
  unsigned short* poolPbf = (unsigned short*)alloc((size_t)Bb * L * HDd * 2);
  unsigned short* poolSbf = (unsigned short*)alloc((size_t)Bb * L * HDd * 2);

  // ---- convert inputs, transpose weights to N x K ----
  {
    const int n4 = (Bb * L * Dd) / 4;
    cvt_bf16_v4<<<dim3((n4 + 255) / 256), dim3(256), 0, stream>>>((const float4*)primary, (ushort4*)Pbf, n4);
    cvt_bf16_v4<<<dim3((n4 + 255) / 256), dim3(256), 0, stream>>>((const float4*)secondary, (ushort4*)Sbf, n4);
  }
  trans_bf16<<<dim3(Dd / 32, Dd / 32, Hh), dim3(256), 0, stream>>>(W_aff, Wcomb, Dd, Dd);
  trans_bf16<<<dim3(INNER / 32, Dd / 32, 1), dim3(256), 0, stream>>>(W_p, Wcomb + (size_t)Hh * Dd * Dd, Dd, INNER);
  trans_bf16<<<dim3(INNER / 32, Dd / 32, 1), dim3(256), 0, stream>>>(W_s, WsT, Dd, INNER);
  trans_bf16<<<dim3(Dd / 32, CAT / 32, 1), dim3(256), 0, stream>>>(W_fp, WfpT, CAT, Dd);
  trans_bf16<<<dim3(Dd / 32, CAT / 32, 1), dim3(256), 0, stream>>>(W_fs, WfsT, CAT, Dd);

  hipMemsetAsync(pool_p, 0, (size_t)Bb * L * HDd * 4, stream);
  hipMemsetAsync(pool_s, 0, (size_t)Bb * L * HDd * 4, stream);

  // ---- wideC = P @ [Waff_0..Waff_7 | W_p]  (merged g1 + pp; M=8192, N=5120, K=512) ----
  {
    GemmP g{};
    g.A = Pbf; g.lda = Dd;
    g.Bm = Wcomb; g.ldb = Dd;
    g.C = wideC; g.ldc = NW;
    g.M = Bb * L; g.N = NW; g.K = Dd; g.Hh = 1;
    run_gemm<0, 1, 0>(g, 1, stream);
  }
  // ---- psb = S @ W_s ----
  {
    GemmP g{};
    g.A = Sbf; g.lda = Dd;
    g.Bm = WsT; g.ldb = Dd;
    g.C = psb; g.ldc = INNER;
    g.M = Bb * L; g.N = INNER; g.K = Dd; g.Hh = 1;
    run_gemm<0, 1, 0>(g, 1, stream);
  }

  // ---- aff[b,h] = tanh(T[b,h] @ S_b^T) * mask ; T lives in wideC cols h*512.. ----
  {
    GemmP g{};
    g.A = wideC; g.lda = NW; g.sAb = (long long)L * NW; g.sAh = Dd;
    g.Bm = Sbf; g.ldb = Dd; g.sBb = LD; g.sBh = 0;
    g.C = affb; g.ldc = L; g.sCb = (long long)Hh * LL; g.sCh = LL;
    g.mask_p = pmask; g.mask_s = smask;
    g.M = L; g.N = L; g.K = Dd; g.Hh = Hh;
    run_gemm<0, 1, 1>(g, Bb * Hh, stream);
  }

  // ---- pool_s max= relu(aff[b,h] @ ps[b][:, h*HD:]) ----
  GemmP g4{};
  g4.A = affb; g4.lda = L; g4.sAb = (long long)Hh * LL; g4.sAh = LL;
  g4.Bm = psb; g4.ldb = INNER; g4.sBb = (long long)L * INNER; g4.sBh = HDd;
  g4.C = pool_s; g4.ldc = HDd; g4.sCb = (long long)L * HDd; g4.sCh = 0;
  g4.M = L; g4.N = HDd; g4.K = L; g4.Hh = Hh;
  run_gemm<0, 0, 2>(g4, Bb * Hh, stream);

  // ---- pool_p max= relu(aff[b,h]^T @ pp[b][:, h*HD:]) ; pp lives in wideC cols 4096.. ----
  {
    GemmP g5 = g4;
    g5.Bm = wideC + (size_t)Hh * Dd; g5.ldb = NW; g5.sBb = (long long)L * NW; g5.sBh = HDd;
    g5.C = pool_p;
    run_gemm<1, 0, 2>(g5, Bb * Hh, stream);
  }

  // ---- pools -> bf16 for piecewise-A FFN staging ----
  {
    const int n4 = (Bb * L * HDd) / 4;
    cvt_bf16_v4<<<dim3((n4 + 255) / 256), dim3(256), 0, stream>>>((const float4*)pool_s, (ushort4*)poolSbf, n4);
    cvt_bf16_v4<<<dim3((n4 + 255) / 256), dim3(256), 0, stream>>>((const float4*)pool_p, (ushort4*)poolPbf, n4);
  }

  // ---- output FFNs: A = [X | pool] piecewise at k=512 (no concat materialization) ----
  GemmP g6{};
  g6.A = Pbf; g6.lda = Dd;
  g6.A2 = poolSbf; g6.lda2 = HDd; g6.kSplit = Dd;
  g6.Bm = WfpT; g6.ldb = CAT;
  g6.C = d_out; g6.ldc = Dd;
  g6.bias = b_fp;
  g6.M = Bb * L; g6.N = Dd; g6.K = CAT; g6.Hh = 1;
  run_gemm<0, 1, 3>(g6, 1, stream);

  g6.A = Sbf; g6.A2 = poolPbf;
  g6.Bm = WfsT;
  g6.C = (float*)d_out + (size_t)Bb * L * Dd;
  g6.bias = b_fs;
  run_gemm<0, 1, 3>(g6, 1, stream);
}